// Round 6
// baseline (227.150 us; speedup 1.0000x reference)
//
#include <hip/hip_runtime.h>

// GNN_Critic: 2-layer SAGEConv (F: 1 -> 16 -> 1) + global_add_pool.
// p[n] = h[n,:].W2l (edge-aggregated -> s2), q[n] = h[n,:].W2r; the 16-dim
// hidden vector is never materialized.
//
// Round-6: round-5's fused structure (P=256 dst-parts of 782 nodes, one
// block per part owns bin+node compute end-to-end) but the partition kernel
// is rewritten as a deterministic two-phase counting scatter: per 8192-edge
// tile, LDS histogram -> one global tail-atomic per nonempty part to reserve
// a contiguous range -> LDS-cursor placement with direct global writes.
// Every LDS dependency is barrier-separated; no rings, no reservation
// retraction, no dynamic LDS. Round-5's ring protocol failed only under
// graph-replay timing (direct call passed) — classic unprovable-race smell.

#define PARTS     256
#define BLK       1024
#define EPT       8             // edges per thread per tile
#define TILE      (BLK * EPT)   // 8192
#define PGRID     256           // partition blocks (1/CU)
#define BINSMAX   800           // bins = ceil(N/PARTS) = 782 for N=200000
#define CNT_ONE   (1u << 25)    // bin1 count field bits [31:25] (deg <= 127)
#define FX_BIAS   131072        // 2^17 per-add bias keeps sum field positive
#define SCALE     4096.0f       // 2^12 fixed-point scale
#define INV_SCALE (1.0f / 4096.0f)

// ---------------------------------------------------------------------------
// Deterministic counting partition. Tiles are distributed round-robin over
// PGRID blocks. Per tile: histogram parts in LDS, reserve per-part global
// ranges with one tail-atomic each, place edges via LDS cursors.
__global__ __launch_bounds__(BLK) void partition_kernel(
    const int* __restrict__ ei, unsigned* __restrict__ pairs,
    unsigned* __restrict__ tails, int E, int bins, unsigned Mdiv, int cap,
    int T) {
    __shared__ unsigned hist[PARTS], curs[PARTS], gbase[PARTS];
    const int tid = threadIdx.x;

    for (int t = blockIdx.x; t < T; t += PGRID) {
        for (int j = tid; j < PARTS; j += BLK) { hist[j] = 0; curs[j] = 0; }
        __syncthreads();

        int eb = t * TILE + tid * EPT;
        int nv = E - eb; nv = nv < 0 ? 0 : (nv > EPT ? EPT : nv);
        int srcv[EPT], dstv[EPT];
        if (nv == EPT && ((E & 3) == 0)) {
            const int4* s4 = (const int4*)(ei + eb);
            const int4* d4 = (const int4*)(ei + E + eb);
            int4 a = s4[0], b = s4[1];
            srcv[0] = a.x; srcv[1] = a.y; srcv[2] = a.z; srcv[3] = a.w;
            srcv[4] = b.x; srcv[5] = b.y; srcv[6] = b.z; srcv[7] = b.w;
            int4 c = d4[0], d = d4[1];
            dstv[0] = c.x; dstv[1] = c.y; dstv[2] = c.z; dstv[3] = c.w;
            dstv[4] = d.x; dstv[5] = d.y; dstv[6] = d.z; dstv[7] = d.w;
        } else {
            for (int k = 0; k < nv; ++k) {
                srcv[k] = ei[eb + k]; dstv[k] = ei[E + eb + k];
            }
        }

        unsigned w[EPT]; int pt[EPT];
#pragma unroll
        for (int k = 0; k < EPT; ++k) {
            if (k < nv) {
                unsigned dst = (unsigned)dstv[k];
                unsigned pp = (unsigned)(((unsigned long long)dst * Mdiv) >> 32);
                int ld = (int)dst - (int)pp * bins;
                while (ld >= bins) { ld -= bins; ++pp; }
                while (ld < 0)     { ld += bins; --pp; }
                pt[k] = (int)pp;
                w[k] = ((unsigned)srcv[k] << 10) | (unsigned)ld;
                atomicAdd(&hist[pp], 1u);
            }
        }
        __syncthreads();

        if (tid < PARTS) {
            unsigned h = hist[tid];
            gbase[tid] = h ? atomicAdd(&tails[tid], h) : 0u;
        }
        __syncthreads();

#pragma unroll
        for (int k = 0; k < EPT; ++k) {
            if (k < nv) {
                unsigned slot = atomicAdd(&curs[pt[k]], 1u);
                unsigned idx = gbase[pt[k]] + slot;
                if (idx < (unsigned)cap)        // safety net; cap is ~26 sigma
                    pairs[(size_t)pt[k] * cap + idx] = w[k];
            }
        }
        __syncthreads();
    }
}

// ---------------------------------------------------------------------------
// Fused bin1 + node pass 1. One block per part: bins (cnt, sum x[src]) in
// LDS, then computes deg, p = h.W2l, q = h.W2r for its <=782 nodes.
__global__ __launch_bounds__(BLK) void bin1_kernel(
    const unsigned* __restrict__ pairs, const unsigned* __restrict__ tails,
    const float* __restrict__ x,
    const float* __restrict__ W1l, const float* __restrict__ b1,
    const float* __restrict__ W1r, const float* __restrict__ W2l,
    const float* __restrict__ W2r,
    float* __restrict__ deg, float* __restrict__ pv, float* __restrict__ qv,
    int N, int bins, int cap) {
    __shared__ unsigned sb[BINSMAX];
    __shared__ float s_w1l[16], s_b1[16], s_w1r[16], s_w2l[16], s_w2r[16];
    const int tid = threadIdx.x;
    const int p = blockIdx.x;
    if (tid < 16) {
        s_w1l[tid] = W1l[tid]; s_b1[tid] = b1[tid]; s_w1r[tid] = W1r[tid];
        s_w2l[tid] = W2l[tid]; s_w2r[tid] = W2r[tid];
    }
    for (int j = tid; j < bins; j += BLK) sb[j] = 0;
    __syncthreads();

    int len = (int)tails[p]; if (len > cap) len = cap;
    const unsigned* bp = pairs + (size_t)p * cap;
    int n4 = len >> 2;
    const uint4* bp4 = (const uint4*)bp;
    for (int e = tid; e < n4; e += BLK) {
        uint4 wq = bp4[e];
        atomicAdd(&sb[wq.x & 1023u],
                  CNT_ONE + (unsigned)((int)rintf(x[wq.x >> 10] * SCALE) + FX_BIAS));
        atomicAdd(&sb[wq.y & 1023u],
                  CNT_ONE + (unsigned)((int)rintf(x[wq.y >> 10] * SCALE) + FX_BIAS));
        atomicAdd(&sb[wq.z & 1023u],
                  CNT_ONE + (unsigned)((int)rintf(x[wq.z >> 10] * SCALE) + FX_BIAS));
        atomicAdd(&sb[wq.w & 1023u],
                  CNT_ONE + (unsigned)((int)rintf(x[wq.w >> 10] * SCALE) + FX_BIAS));
    }
    for (int e = (n4 << 2) + tid; e < len; e += BLK) {
        unsigned wv = bp[e];
        atomicAdd(&sb[wv & 1023u],
                  CNT_ONE + (unsigned)((int)rintf(x[wv >> 10] * SCALE) + FX_BIAS));
    }
    __syncthreads();

    int lo = p * bins;
    int nb = N - lo; if (nb > bins) nb = bins;
    for (int j = tid; j < nb; j += BLK) {
        unsigned w = sb[j];
        unsigned c = w >> 25;
        float dg  = (float)c;
        float sum = (float)(int)((w & (CNT_ONE - 1)) - c * (unsigned)FX_BIAS) * INV_SCALE;
        float m   = sum / fmaxf(dg, 1.0f);
        float xv  = x[lo + j];
        float pa = 0.0f, qa = 0.0f;
#pragma unroll
        for (int f = 0; f < 16; ++f) {
            float h = fmaf(m, s_w1l[f], fmaf(xv, s_w1r[f], s_b1[f]));
            h = fmaxf(h, 0.0f);
            pa = fmaf(h, s_w2l[f], pa);
            qa = fmaf(h, s_w2r[f], qa);
        }
        deg[lo + j] = dg;
        pv[lo + j]  = pa;
        qv[lo + j]  = qa;
    }
}

// ---------------------------------------------------------------------------
// Fused bin2 + node pass 2 + pool. One block per part: bins sum p[src] in
// LDS, then h2 = s2/max(deg,1)+b2+q per node and wave-segmented pool into
// out[batch[n]] (batch sorted; bins <= BLK so one node per thread).
__global__ __launch_bounds__(BLK) void bin2_kernel(
    const unsigned* __restrict__ pairs, const unsigned* __restrict__ tails,
    const float* __restrict__ pv, const float* __restrict__ deg,
    const float* __restrict__ qv, const float* __restrict__ b2,
    const int* __restrict__ batch, float* __restrict__ out,
    int N, int bins, int cap) {
    __shared__ int sbi[BINSMAX];
    const int tid = threadIdx.x;
    const int p = blockIdx.x;
    for (int j = tid; j < bins; j += BLK) sbi[j] = 0;
    __syncthreads();

    int len = (int)tails[p]; if (len > cap) len = cap;
    const unsigned* bp = pairs + (size_t)p * cap;
    int n4 = len >> 2;
    const uint4* bp4 = (const uint4*)bp;
    for (int e = tid; e < n4; e += BLK) {
        uint4 wq = bp4[e];
        atomicAdd(&sbi[wq.x & 1023u], (int)rintf(pv[wq.x >> 10] * SCALE));
        atomicAdd(&sbi[wq.y & 1023u], (int)rintf(pv[wq.y >> 10] * SCALE));
        atomicAdd(&sbi[wq.z & 1023u], (int)rintf(pv[wq.z >> 10] * SCALE));
        atomicAdd(&sbi[wq.w & 1023u], (int)rintf(pv[wq.w >> 10] * SCALE));
    }
    for (int e = (n4 << 2) + tid; e < len; e += BLK) {
        unsigned wv = bp[e];
        atomicAdd(&sbi[wv & 1023u], (int)rintf(pv[wv >> 10] * SCALE));
    }
    __syncthreads();

    int lo = p * bins;
    int nb = N - lo; if (nb > bins) nb = bins;   // nb <= bins <= BLK
    float b2v = b2[0];
    float val = 0.0f;
    int g;
    if (tid < nb) {
        float s2 = (float)sbi[tid] * INV_SCALE;
        val = s2 / fmaxf(deg[lo + tid], 1.0f) + b2v + qv[lo + tid];
        g = batch[lo + tid];
    } else {
        g = batch[lo + nb - 1];  // pad lanes contribute 0 to a valid graph id
    }
    int g0 = __shfl(g, 0);
    unsigned long long same = __ballot(g == g0);
    if (same == ~0ULL) {
        for (int off = 32; off > 0; off >>= 1) val += __shfl_down(val, off);
        if ((tid & 63) == 0) atomicAdd(&out[g0], val);
    } else {
        atomicAdd(&out[g], val);
    }
}

// ---------------------------------------------------------------------------
extern "C" void kernel_launch(void* const* d_in, const int* in_sizes, int n_in,
                              void* d_out, int out_size, void* d_ws, size_t ws_size,
                              hipStream_t stream) {
    const float* x     = (const float*)d_in[0];
    const int*   ei    = (const int*)d_in[1];   // [2, E] flat: src then dst
    const int*   batch = (const int*)d_in[2];
    const float* W1l = (const float*)d_in[4];
    const float* b1  = (const float*)d_in[5];
    const float* W1r = (const float*)d_in[6];
    const float* W2l = (const float*)d_in[7];
    const float* b2  = (const float*)d_in[8];
    const float* W2r = (const float*)d_in[9];

    const int N = in_sizes[0];        // 200000
    const int E = in_sizes[1] / 2;    // 6400000
    float* out = (float*)d_out;       // [512]

    const int bins = (N + PARTS - 1) / PARTS;   // 782 (needs <= 1024)
    const unsigned Mdiv =
        (unsigned)(((1ULL << 32) + (unsigned)bins - 1) / (unsigned)bins);
    const int EperP = E / PARTS;                // 25000
    int cap = ((EperP + EperP / 8 + 1024) + 1023) & ~1023;   // ~26-sigma margin
    int T = (E + TILE - 1) / TILE;              // 782 tiles

    // workspace (u32 words): pairs[PARTS][cap] | deg[N] | p[N] | q[N] | tails
    unsigned* pairs = (unsigned*)d_ws;
    float* deg = (float*)(pairs + (size_t)PARTS * cap);
    float* pv  = deg + N;
    float* qv  = pv + N;
    unsigned* tails = (unsigned*)(qv + N);

    hipMemsetAsync(d_out, 0, (size_t)out_size * sizeof(float), stream);
    hipMemsetAsync(tails, 0, PARTS * sizeof(unsigned), stream);

    partition_kernel<<<PGRID, BLK, 0, stream>>>(ei, pairs, tails,
                                                E, bins, Mdiv, cap, T);
    bin1_kernel<<<PARTS, BLK, 0, stream>>>(pairs, tails, x, W1l, b1, W1r,
                                           W2l, W2r, deg, pv, qv, N, bins, cap);
    bin2_kernel<<<PARTS, BLK, 0, stream>>>(pairs, tails, pv, deg, qv, b2,
                                           batch, out, N, bins, cap);
}